// Round 3
// baseline (212.815 us; speedup 1.0000x reference)
//
#include <hip/hip_runtime.h>
#include <hip/hip_bf16.h>

// B=2, N=512. row = b*512 + i, rows 0..1023.
// Fused single-kernel version: 256 blocks x 512 threads; block handles 4 rows,
// each row gets 2 waves (w=0,1) splitting its edge list. Grid-wide sync via
// manual device-scope barrier (counters zeroed by hipMemsetAsync each call).
//
// EdgeConv factorization: e@W1 = x_i@(W1_top - W1_bot) + x_j@W1_bot
//   u_i = x_i@(W1_top-W1_bot)+b1 ; v_j = x_j@W1_bot ; h1 = relu(u_i+v_j)
// Masked max over neighbors only (A>0) is exact: h2 = relu(..) >= 0 > -1e9.
// Residuals stay in registers (block == row owner across all phases).

#define NEGV -1e9f
#define MAXNBR 96
#define NBLK 256

__device__ __forceinline__ void gsync(int* bar, int nblk) {
  __syncthreads();  // drains each wave's vmcnt -> stores in L2
  if (threadIdx.x == 0) {
    __threadfence();  // agent-scope release (L2 writeback)
    __hip_atomic_fetch_add(bar, 1, __ATOMIC_ACQ_REL, __HIP_MEMORY_SCOPE_AGENT);
    while (__hip_atomic_load(bar, __ATOMIC_ACQUIRE,
                             __HIP_MEMORY_SCOPE_AGENT) < nblk) {
      __builtin_amdgcn_s_sleep(2);
    }
    __threadfence();  // agent-scope acquire (invalidate stale lines)
  }
  __syncthreads();
}

// Per-wave edge-max partial: this wave handles edges [beg,end) of its row.
// Barrier-free: h-buffer producer and consumer are the same wave (DS ops are
// in-order within a wave), so v-prefetch global loads stay in flight across
// groups. hbuf layout [channel][edge-in-group] -> b128 broadcast reads.
__device__ __forceinline__ float edge_partial(
    int row, int w, int o, int cnt, const int* nbr,
    const float* __restrict__ u, const float* __restrict__ v,
    const float* __restrict__ W2, const float* __restrict__ b2, float* hbuf) {
  float wcol[64];
#pragma unroll
  for (int k = 0; k < 64; k++) wcol[k] = W2[k * 64 + o];
  float ui = u[row * 64 + o];
  float bo = b2[o];
  const float* vb = v + (size_t)(row >> 9) * (512 * 64);
  int half = (cnt + 1) >> 1;
  int beg = w ? half : 0;
  int myc = (w ? cnt : half) - beg;
  float acc = NEGV;
  if (myc > 0) {
    float vl[4];
#pragma unroll
    for (int t = 0; t < 4; t++) {
      int e = t < myc ? t : myc - 1;
      vl[t] = vb[nbr[beg + e] * 64 + o];
    }
    for (int e0 = 0; e0 < myc; e0 += 4) {
      float4 hw;
      hw.x = fmaxf(ui + vl[0], 0.f);
      hw.y = fmaxf(ui + vl[1], 0.f);
      hw.z = fmaxf(ui + vl[2], 0.f);
      hw.w = fmaxf(ui + vl[3], 0.f);
      *(float4*)(hbuf + o * 4) = hw;
      if (e0 + 4 < myc) {
#pragma unroll
        for (int t = 0; t < 4; t++) {
          int e = e0 + 4 + t;
          if (e >= myc) e = myc - 1;
          vl[t] = vb[nbr[beg + e] * 64 + o];  // prefetch next group
        }
      }
      float s0 = bo, s1 = bo, s2 = bo, s3 = bo;
#pragma unroll
      for (int k = 0; k < 64; k++) {
        float4 hv = *(const float4*)(hbuf + k * 4);  // broadcast read
        s0 = fmaf(hv.x, wcol[k], s0);
        s1 = fmaf(hv.y, wcol[k], s1);
        s2 = fmaf(hv.z, wcol[k], s2);
        s3 = fmaf(hv.w, wcol[k], s3);
      }
      acc = fmaxf(acc, fmaxf(s0, 0.f));
      if (e0 + 1 < myc) acc = fmaxf(acc, fmaxf(s1, 0.f));
      if (e0 + 2 < myc) acc = fmaxf(acc, fmaxf(s2, 0.f));
      if (e0 + 3 < myc) acc = fmaxf(acc, fmaxf(s3, 0.f));
    }
  }
  return acc;
}

__global__ __launch_bounds__(512, 2) void fused_gnn(
    const float* __restrict__ coords, const float* __restrict__ A,
    const float* __restrict__ nf, const float* __restrict__ cs,
    const float* __restrict__ Wh1, const float* __restrict__ bh1,
    const float* __restrict__ Wh2, const float* __restrict__ bh2,
    const float* __restrict__ e1W1, const float* __restrict__ e1b1,
    const float* __restrict__ e1W2, const float* __restrict__ e1b2,
    const float* __restrict__ e2W1, const float* __restrict__ e2b1,
    const float* __restrict__ e2W2, const float* __restrict__ e2b2,
    const float* __restrict__ e3W1, const float* __restrict__ e3b1,
    const float* __restrict__ e3W2, const float* __restrict__ e3b2,
    const float* __restrict__ Wh6, const float* __restrict__ bh6,
    const float* __restrict__ Wout, const float* __restrict__ bout,
    float* __restrict__ u1, float* __restrict__ v1, float* __restrict__ u2,
    float* __restrict__ v2, float* __restrict__ u3, float* __restrict__ v3,
    int* __restrict__ bar, float* __restrict__ out) {
  __shared__ int s_nbr[4][MAXNBR];
  __shared__ int s_cnt[4];
  __shared__ float s_xs[4][128];
  __shared__ float s_pm[4][2][64];
  __shared__ float s_h[4][2][64 * 4];
  __shared__ float s_h6[4][128];

  int tid = threadIdx.x;
  int r = tid >> 7;
  int row = blockIdx.x * 4 + r;
  int w = (tid >> 6) & 1;
  int o = tid & 63;

  // ---------- phase 1: nbr build (wave0) || node MLP (wave1) ----------
  if (w == 0) {
    const float* Arow = A + (size_t)row * 512;
    int base = 0;
    for (int c = 0; c < 8; c++) {
      bool p = Arow[c * 64 + o] > 0.f;
      unsigned long long m = __ballot(p);
      if (p) {
        int pos = base + __builtin_popcountll(m & ((1ull << o) - 1ull));
        if (pos < MAXNBR) s_nbr[r][pos] = c * 64 + o;
      }
      base += __builtin_popcountll(m);
    }
    if (o == 0) s_cnt[r] = base < MAXNBR ? base : MAXNBR;
  } else {
    float c0 = coords[row * 3 + 0];
    float c1 = coords[row * 3 + 1];
    float c2 = coords[row * 3 + 2];
    float a = bh1[o];
    a = fmaf(c0, Wh1[o], a);
    a = fmaf(c1, Wh1[64 + o], a);
    a = fmaf(c2, Wh1[128 + o], a);
    s_pm[r][0][o] = fmaxf(a, 0.f);
  }
  __syncthreads();
  if (w == 1) {
    float a2 = bh2[o];
#pragma unroll 8
    for (int k = 0; k < 64; k++) a2 = fmaf(s_pm[r][0][k], Wh2[k * 64 + o], a2);
    s_xs[r][o] = fmaxf(a2, 0.f);
  } else {
    if (o < 63) s_xs[r][64 + o] = nf[row * 63 + o];
    else s_xs[r][127] = cs[row];
  }
  __syncthreads();
  {
    const float* Wb = e1W1 + 128 * 64;
    if (w == 0) {
      float acc = e1b1[o];
#pragma unroll 4
      for (int k = 0; k < 128; k++)
        acc = fmaf(s_xs[r][k], e1W1[k * 64 + o] - Wb[k * 64 + o], acc);
      u1[row * 64 + o] = acc;
    } else {
      float acc = 0.f;
#pragma unroll 4
      for (int k = 0; k < 128; k++)
        acc = fmaf(s_xs[r][k], Wb[k * 64 + o], acc);
      v1[row * 64 + o] = acc;
    }
  }
  gsync(bar + 0, NBLK);

  int cnt = s_cnt[r];

  // ---------- phase 2: EdgeConv1 + u2/v2 ----------
  s_pm[r][w][o] =
      edge_partial(row, w, o, cnt, s_nbr[r], u1, v1, e1W2, e1b2, s_h[r][w]);
  __syncthreads();
  float acc1 = fmaxf(s_pm[r][0][o], s_pm[r][1][o]);
  if (w == 0) s_xs[r][o] = acc1;
  __syncthreads();
  {
    const float* Wb = e2W1 + 64 * 64;
    if (w == 0) {
      float acc = e2b1[o];
#pragma unroll 4
      for (int k = 0; k < 64; k++)
        acc = fmaf(s_xs[r][k], e2W1[k * 64 + o] - Wb[k * 64 + o], acc);
      u2[row * 64 + o] = acc;
    } else {
      float acc = 0.f;
#pragma unroll 4
      for (int k = 0; k < 64; k++) acc = fmaf(s_xs[r][k], Wb[k * 64 + o], acc);
      v2[row * 64 + o] = acc;
    }
  }
  gsync(bar + 32, NBLK);

  // ---------- phase 3: EdgeConv2 + residual + u3/v3 ----------
  s_pm[r][w][o] =
      edge_partial(row, w, o, cnt, s_nbr[r], u2, v2, e2W2, e2b2, s_h[r][w]);
  __syncthreads();
  float acc2 = fmaxf(s_pm[r][0][o], s_pm[r][1][o]);
  if (w == 0) s_xs[r][o] = acc2 + acc1;
  __syncthreads();
  {
    const float* Wb = e3W1 + 64 * 64;
    if (w == 0) {
      float acc = e3b1[o];
#pragma unroll 4
      for (int k = 0; k < 64; k++)
        acc = fmaf(s_xs[r][k], e3W1[k * 64 + o] - Wb[k * 64 + o], acc);
      u3[row * 64 + o] = acc;
    } else {
      float acc = 0.f;
#pragma unroll 4
      for (int k = 0; k < 64; k++) acc = fmaf(s_xs[r][k], Wb[k * 64 + o], acc);
      v3[row * 64 + o] = acc;
    }
  }
  gsync(bar + 64, NBLK);

  // ---------- phase 4: EdgeConv3 + residual + head MLP ----------
  s_pm[r][w][o] =
      edge_partial(row, w, o, cnt, s_nbr[r], u3, v3, e3W2, e3b2, s_h[r][w]);
  __syncthreads();
  float acc3 = fmaxf(s_pm[r][0][o], s_pm[r][1][o]);
  if (w == 0) s_xs[r][o] = acc3 + acc2;
  __syncthreads();
  {
    int t2 = tid & 127;
    float s = bh6[t2];
#pragma unroll 4
    for (int k = 0; k < 64; k++) s = fmaf(s_xs[r][k], Wh6[k * 128 + t2], s);
    s_h6[r][t2] = fmaxf(s, 0.f);
  }
  __syncthreads();
  {
    int t2 = tid & 127;
    if (t2 < 3) {
      float s = bout[t2];
#pragma unroll 8
      for (int k = 0; k < 128; k++) s = fmaf(s_h6[r][k], Wout[k * 3 + t2], s);
      out[row * 3 + t2] = fmaxf(s, 0.f);
    }
  }
}

extern "C" void kernel_launch(void* const* d_in, const int* in_sizes, int n_in,
                              void* d_out, int out_size, void* d_ws,
                              size_t ws_size, hipStream_t stream) {
  const float* coords = (const float*)d_in[0];
  const float* A      = (const float*)d_in[1];
  const float* nf     = (const float*)d_in[2];
  const float* cs     = (const float*)d_in[3];
  const float* Wh1 = (const float*)d_in[4];
  const float* bh1 = (const float*)d_in[5];
  const float* Wh2 = (const float*)d_in[6];
  const float* bh2 = (const float*)d_in[7];
  const float* e1W1 = (const float*)d_in[8];
  const float* e1b1 = (const float*)d_in[9];
  const float* e1W2 = (const float*)d_in[10];
  const float* e1b2 = (const float*)d_in[11];
  const float* e2W1 = (const float*)d_in[12];
  const float* e2b1 = (const float*)d_in[13];
  const float* e2W2 = (const float*)d_in[14];
  const float* e2b2 = (const float*)d_in[15];
  const float* e3W1 = (const float*)d_in[16];
  const float* e3b1 = (const float*)d_in[17];
  const float* e3W2 = (const float*)d_in[18];
  const float* e3b2 = (const float*)d_in[19];
  const float* Wh6 = (const float*)d_in[20];
  const float* bh6 = (const float*)d_in[21];
  const float* Wout = (const float*)d_in[22];
  const float* bout = (const float*)d_in[23];

  float* ws = (float*)d_ws;
  float* u1 = ws + 0 * 65536;
  float* v1 = ws + 1 * 65536;
  float* u2 = ws + 2 * 65536;
  float* v2 = ws + 3 * 65536;
  float* u3 = ws + 4 * 65536;
  float* v3 = ws + 5 * 65536;
  int* bar = (int*)(ws + 6 * 65536);  // 3 counters, 128 B apart

  hipMemsetAsync(bar, 0, 96 * sizeof(int), stream);
  fused_gnn<<<dim3(NBLK), dim3(512), 0, stream>>>(
      coords, A, nf, cs, Wh1, bh1, Wh2, bh2, e1W1, e1b1, e1W2, e1b2, e2W1,
      e2b1, e2W2, e2b2, e3W1, e3b1, e3W2, e3b2, Wh6, bh6, Wout, bout, u1, v1,
      u2, v2, u3, v3, bar, (float*)d_out);
}

// Round 4
// 157.009 us; speedup vs baseline: 1.3554x; 1.3554x over previous
//
#include <hip/hip_runtime.h>
#include <hip/hip_bf16.h>

// B=2, N=512. row = b*512 + i, rows 0..1023.
// 4-kernel structure (no grid sync, no device fences — R3 showed agent fences
// invalidate per-XCD L2 and cost ~100 µs). Block = 128 threads = 2 waves per
// row; waves split the row's edge list, combine via block-local LDS.
//
// EdgeConv factorization: e@W1 = x_i@(W1_top - W1_bot) + x_j@W1_bot
//   u_i = x_i@(W1_top-W1_bot)+b1 ; v_j = x_j@W1_bot ; h1 = relu(u_i+v_j)
// Masked max over neighbors only (A>0) is exact: h2 = relu(..) >= 0 > -1e9.

#define NEGV -1e9f
#define MAXNBR 96

// Per-wave edge-max partial over edges [beg, beg+myc) of this row.
// Barrier-free: hbuf producer == consumer wave (DS ops in-order per wave), so
// the v-prefetch global loads stay in flight across groups.
__device__ __forceinline__ float edge_partial(
    int beg, int myc, int o, const int* nbr, const float* __restrict__ vb,
    float ui, float bo, const float* wcol, float* hbuf) {
  float acc = NEGV;
  if (myc <= 0) return acc;
  float vl[4];
#pragma unroll
  for (int t = 0; t < 4; t++) {
    int e = t < myc ? t : myc - 1;
    vl[t] = vb[nbr[beg + e] * 64 + o];
  }
  for (int e0 = 0; e0 < myc; e0 += 4) {
    float4 hw;
    hw.x = fmaxf(ui + vl[0], 0.f);
    hw.y = fmaxf(ui + vl[1], 0.f);
    hw.z = fmaxf(ui + vl[2], 0.f);
    hw.w = fmaxf(ui + vl[3], 0.f);
    *(float4*)(hbuf + o * 4) = hw;
    if (e0 + 4 < myc) {
#pragma unroll
      for (int t = 0; t < 4; t++) {
        int e = e0 + 4 + t;
        if (e >= myc) e = myc - 1;
        vl[t] = vb[nbr[beg + e] * 64 + o];  // prefetch next group
      }
    }
    float s0 = bo, s1 = bo, s2 = bo, s3 = bo;
#pragma unroll
    for (int k = 0; k < 64; k++) {
      float4 hv = *(const float4*)(hbuf + k * 4);  // broadcast read
      s0 = fmaf(hv.x, wcol[k], s0);
      s1 = fmaf(hv.y, wcol[k], s1);
      s2 = fmaf(hv.z, wcol[k], s2);
      s3 = fmaf(hv.w, wcol[k], s3);
    }
    acc = fmaxf(acc, fmaxf(s0, 0.f));
    if (e0 + 1 < myc) acc = fmaxf(acc, fmaxf(s1, 0.f));
    if (e0 + 2 < myc) acc = fmaxf(acc, fmaxf(s2, 0.f));
    if (e0 + 3 < myc) acc = fmaxf(acc, fmaxf(s3, 0.f));
  }
  return acc;
}

// K1: neighbor-list build + node MLP (3->64->64) + concat -> x0[128] + u1/v1.
__global__ __launch_bounds__(64) void k1_node_uv(
    const float* __restrict__ coords, const float* __restrict__ A,
    const float* __restrict__ nf, const float* __restrict__ cs,
    const float* __restrict__ Wh1, const float* __restrict__ bh1,
    const float* __restrict__ Wh2, const float* __restrict__ bh2,
    const float* __restrict__ W1, const float* __restrict__ b1,
    float* __restrict__ u, float* __restrict__ v,
    int* __restrict__ nbrCnt, int* __restrict__ nbrG) {
  int node = blockIdx.x;
  int o = threadIdx.x;
  __shared__ float t[64];
  __shared__ float xs[128];
  {
    const float* Arow = A + (size_t)node * 512;
    int base = 0;
    for (int c = 0; c < 8; c++) {
      bool p = Arow[c * 64 + o] > 0.f;
      unsigned long long m = __ballot(p);
      if (p) {
        int pos = base + __builtin_popcountll(m & ((1ull << o) - 1ull));
        if (pos < MAXNBR) nbrG[node * MAXNBR + pos] = c * 64 + o;
      }
      base += __builtin_popcountll(m);
    }
    if (o == 0) nbrCnt[node] = base < MAXNBR ? base : MAXNBR;
  }
  float c0 = coords[node * 3 + 0];
  float c1 = coords[node * 3 + 1];
  float c2 = coords[node * 3 + 2];
  float a = bh1[o];
  a = fmaf(c0, Wh1[o], a);
  a = fmaf(c1, Wh1[64 + o], a);
  a = fmaf(c2, Wh1[128 + o], a);
  t[o] = fmaxf(a, 0.f);
  __syncthreads();
  float a2 = bh2[o];
#pragma unroll 8
  for (int k = 0; k < 64; k++) a2 = fmaf(t[k], Wh2[k * 64 + o], a2);
  xs[o] = fmaxf(a2, 0.f);
  if (o < 63) xs[64 + o] = nf[node * 63 + o];
  if (o == 63) xs[127] = cs[node];
  __syncthreads();
  float ua = b1[o], va = 0.f;
#pragma unroll 4
  for (int k = 0; k < 128; k++) {
    float xk = xs[k];
    float wt = W1[k * 64 + o];
    float wb = W1[(128 + k) * 64 + o];
    ua = fmaf(xk, wt - wb, ua);
    va = fmaf(xk, wb, va);
  }
  u[node * 64 + o] = ua;
  v[node * 64 + o] = va;
}

// K2/K3: EdgeConv (+opt residual) ; writes raw out and u/v for next layer.
// Block = 128 threads (2 waves), one row per block.
__global__ __launch_bounds__(128) void k_edgeconv_uv(
    const int* __restrict__ nbrCnt, const int* __restrict__ nbrG,
    const float* __restrict__ u, const float* __restrict__ v,
    const float* __restrict__ W2, const float* __restrict__ b2,
    const float* __restrict__ res,  // may be null
    float* __restrict__ raw_out,
    const float* __restrict__ W1n, const float* __restrict__ b1n,
    float* __restrict__ un, float* __restrict__ vn) {
  __shared__ int s_nbr[MAXNBR];
  __shared__ float s_h[2][64 * 4];
  __shared__ float s_pm[2][64];
  __shared__ float s_xs[64];
  int row = blockIdx.x;
  int tid = threadIdx.x;
  int w = tid >> 6, o = tid & 63;
  int cnt = __builtin_amdgcn_readfirstlane(nbrCnt[row]);
  if (tid < MAXNBR) s_nbr[tid] = (tid < cnt) ? nbrG[row * MAXNBR + tid] : 0;
  float wcol[64];
#pragma unroll
  for (int k = 0; k < 64; k++) wcol[k] = W2[k * 64 + o];
  float ui = u[row * 64 + o];
  float bo = b2[o];
  const float* vb = v + (size_t)(row >> 9) * (512 * 64);
  __syncthreads();
  int half = (cnt + 1) >> 1;
  int beg = w ? half : 0;
  int myc = (w ? cnt : half) - beg;
  s_pm[w][o] = edge_partial(beg, myc, o, s_nbr, vb, ui, bo, wcol, s_h[w]);
  __syncthreads();
  float acc = fmaxf(s_pm[0][o], s_pm[1][o]);
  if (w == 0) {
    raw_out[row * 64 + o] = acc;
    s_xs[o] = acc + (res ? res[row * 64 + o] : 0.f);
  }
  __syncthreads();
  const float* Wb = W1n + 64 * 64;
  if (w == 0) {
    float a = b1n[o];
#pragma unroll 4
    for (int k = 0; k < 64; k++)
      a = fmaf(s_xs[k], W1n[k * 64 + o] - Wb[k * 64 + o], a);
    un[row * 64 + o] = a;
  } else {
    float a = 0.f;
#pragma unroll 4
    for (int k = 0; k < 64; k++) a = fmaf(s_xs[k], Wb[k * 64 + o], a);
    vn[row * 64 + o] = a;
  }
}

// K4: EdgeConv3 + residual(ec2_raw) + head MLP 64->128->3 (both relu).
__global__ __launch_bounds__(128) void k_edgeconv_final(
    const int* __restrict__ nbrCnt, const int* __restrict__ nbrG,
    const float* __restrict__ u, const float* __restrict__ v,
    const float* __restrict__ W2, const float* __restrict__ b2,
    const float* __restrict__ res,
    const float* __restrict__ Wh6, const float* __restrict__ bh6,
    const float* __restrict__ Wout, const float* __restrict__ bout,
    float* __restrict__ out) {
  __shared__ int s_nbr[MAXNBR];
  __shared__ float s_h[2][64 * 4];
  __shared__ float s_pm[2][64];
  __shared__ float s_xs[64];
  __shared__ float s_h6[128];
  int row = blockIdx.x;
  int tid = threadIdx.x;
  int w = tid >> 6, o = tid & 63;
  int cnt = __builtin_amdgcn_readfirstlane(nbrCnt[row]);
  if (tid < MAXNBR) s_nbr[tid] = (tid < cnt) ? nbrG[row * MAXNBR + tid] : 0;
  float wcol[64];
#pragma unroll
  for (int k = 0; k < 64; k++) wcol[k] = W2[k * 64 + o];
  float ui = u[row * 64 + o];
  float bo = b2[o];
  const float* vb = v + (size_t)(row >> 9) * (512 * 64);
  __syncthreads();
  int half = (cnt + 1) >> 1;
  int beg = w ? half : 0;
  int myc = (w ? cnt : half) - beg;
  s_pm[w][o] = edge_partial(beg, myc, o, s_nbr, vb, ui, bo, wcol, s_h[w]);
  __syncthreads();
  if (w == 0) {
    float acc = fmaxf(s_pm[0][o], s_pm[1][o]);
    s_xs[o] = acc + res[row * 64 + o];
  }
  __syncthreads();
  {
    float s = bh6[tid];
#pragma unroll 4
    for (int k = 0; k < 64; k++) s = fmaf(s_xs[k], Wh6[k * 128 + tid], s);
    s_h6[tid] = fmaxf(s, 0.f);
  }
  __syncthreads();
  if (tid < 3) {
    float s = bout[tid];
#pragma unroll 8
    for (int k = 0; k < 128; k++) s = fmaf(s_h6[k], Wout[k * 3 + tid], s);
    out[row * 3 + tid] = fmaxf(s, 0.f);
  }
}

extern "C" void kernel_launch(void* const* d_in, const int* in_sizes, int n_in,
                              void* d_out, int out_size, void* d_ws,
                              size_t ws_size, hipStream_t stream) {
  const float* coords = (const float*)d_in[0];
  const float* A      = (const float*)d_in[1];
  const float* nf     = (const float*)d_in[2];
  const float* cs     = (const float*)d_in[3];
  const float* Wh1 = (const float*)d_in[4];
  const float* bh1 = (const float*)d_in[5];
  const float* Wh2 = (const float*)d_in[6];
  const float* bh2 = (const float*)d_in[7];
  const float* e1W1 = (const float*)d_in[8];
  const float* e1b1 = (const float*)d_in[9];
  const float* e1W2 = (const float*)d_in[10];
  const float* e1b2 = (const float*)d_in[11];
  const float* e2W1 = (const float*)d_in[12];
  const float* e2b1 = (const float*)d_in[13];
  const float* e2W2 = (const float*)d_in[14];
  const float* e2b2 = (const float*)d_in[15];
  const float* e3W1 = (const float*)d_in[16];
  const float* e3b1 = (const float*)d_in[17];
  const float* e3W2 = (const float*)d_in[18];
  const float* e3b2 = (const float*)d_in[19];
  const float* Wh6 = (const float*)d_in[20];
  const float* bh6 = (const float*)d_in[21];
  const float* Wout = (const float*)d_in[22];
  const float* bout = (const float*)d_in[23];

  float* ws = (float*)d_ws;
  float* u1  = ws + 0 * 65536;
  float* v1  = ws + 1 * 65536;
  float* e1o = ws + 2 * 65536;
  float* u2  = ws + 3 * 65536;
  float* v2  = ws + 4 * 65536;
  float* e2r = ws + 5 * 65536;
  float* u3  = ws + 6 * 65536;
  float* v3  = ws + 7 * 65536;
  int* wsI = (int*)(ws + 8 * 65536);
  int* nbrCnt = wsI;         // 1024 ints
  int* nbrG   = wsI + 1024;  // 1024*96 ints
  float* out = (float*)d_out;

  k1_node_uv<<<dim3(1024), dim3(64), 0, stream>>>(
      coords, A, nf, cs, Wh1, bh1, Wh2, bh2, e1W1, e1b1, u1, v1, nbrCnt, nbrG);
  k_edgeconv_uv<<<dim3(1024), dim3(128), 0, stream>>>(
      nbrCnt, nbrG, u1, v1, e1W2, e1b2, nullptr, e1o, e2W1, e2b1, u2, v2);
  k_edgeconv_uv<<<dim3(1024), dim3(128), 0, stream>>>(
      nbrCnt, nbrG, u2, v2, e2W2, e2b2, e1o, e2r, e3W1, e3b1, u3, v3);
  k_edgeconv_final<<<dim3(1024), dim3(128), 0, stream>>>(
      nbrCnt, nbrG, u3, v3, e3W2, e3b2, e2r, Wh6, bh6, Wout, bout, out);
}